// Round 8
// baseline (458.704 us; speedup 1.0000x reference)
//
#include <hip/hip_runtime.h>
#include <hip/hip_bf16.h>

// ShrinkingUnit: N=16, I=4096, C=16, P=16, K=8, CP=32, NI=65536.
// Math reduction: mean-aggregated bilinear message
//   aggr[i,p] = sum_c x_i[c] * (sum_c' tbar[c'] F_W[c',p*16+c] + F_b[p*16+c]),
//   tbar_i = s_i/deg_i - x_i,  s_i = sum of x_src over incoming edges.
// So edges only need a 16-dim segment-sum + degree count.

__device__ __forceinline__ unsigned fmap(float f) {
    unsigned u = __float_as_uint(f);
    return (u & 0x80000000u) ? ~u : (u | 0x80000000u);   // order-preserving map
}
__device__ __forceinline__ float funmap(unsigned m) {
    return (m & 0x80000000u) ? __uint_as_float(m & 0x7FFFFFFFu)
                             : __uint_as_float(~m);
}

__device__ __forceinline__ void load16(const float* __restrict__ p, float* r) {
    const float4* q = (const float4*)p;
    float4 a = q[0], b = q[1], c = q[2], d = q[3];
    r[0]=a.x; r[1]=a.y; r[2]=a.z; r[3]=a.w;
    r[4]=b.x; r[5]=b.y; r[6]=b.z; r[7]=b.w;
    r[8]=c.x; r[9]=c.y; r[10]=c.z; r[11]=c.w;
    r[12]=d.x; r[13]=d.y; r[14]=d.z; r[15]=d.w;
}

// ---------------------------------------------------------------- edges
__global__ __launch_bounds__(256) void edge_scatter(
    const float* __restrict__ x, const int* __restrict__ ei,
    float* __restrict__ s, float* __restrict__ deg, int E)
{
    int tid = blockIdx.x * 256 + threadIdx.x;
    int e = tid >> 4, c = tid & 15;
    if (e >= E) return;
    int src = ei[e];          // row 0 = src
    int dst = ei[E + e];      // row 1 = dst
    atomicAdd(&s[(size_t)dst * 16 + c], x[(size_t)src * 16 + c]);
    if (c == 0) atomicAdd(&deg[dst], 1.0f);
}

// ---------------------------------------------------------------- nodes
// 2 threads per node (each handles 16 of the 32 p's). Weights staged in LDS
// (F first, then re-staged as W). aF kept in padded LDS (stride 17) so loops
// stay rolled without scratch spills.
__global__ __launch_bounds__(256) void node_update(
    const float* __restrict__ x, const float* __restrict__ s,
    const float* __restrict__ deg,
    const float* __restrict__ Fw, const float* __restrict__ Fb,
    const float* __restrict__ Ww, const float* __restrict__ Wb,
    const float* __restrict__ Mw, const float* __restrict__ Mb,
    const float* __restrict__ Bv,
    float* __restrict__ conv, float* __restrict__ S1s, float* __restrict__ S2s)
{
    __shared__ float wlds[8192];      // 16 x 512 weight tile (F, then W)
    __shared__ float aF[256 * 17];    // per-thread 16 aF values, pad 17
    const int tid = threadIdx.x;
    #pragma unroll
    for (int k = 0; k < 8192; k += 256) wlds[k + tid] = Fw[k + tid];

    const int gt = blockIdx.x * 256 + tid;
    const int i  = gt >> 1;           // node
    const int h  = gt & 1;            // which 16-p half
    const int n  = i >> 12;           // cloud (I = 4096)

    float xr[16], tr[16];
    load16(x + (size_t)i * 16, xr);
    load16(s + (size_t)i * 16, tr);
    const float invd = 1.0f / deg[i];
    #pragma unroll
    for (int c = 0; c < 16; ++c) tr[c] = tr[c] * invd - xr[c];

    __syncthreads();                  // F staged

    const int pbase = h << 8;         // colBase = (h*16+pp)*16 = h*256 + pp*16
    // phase 1: aF[p] = x^T (tbar^T F)_p
    #pragma unroll 1
    for (int pp = 0; pp < 16; ++pp) {
        const int cb0 = pbase + (pp << 4);
        float acc = 0.0f;
        #pragma unroll
        for (int cb = 0; cb < 16; cb += 4) {
            float u0 = Fb[cb0+cb+0], u1 = Fb[cb0+cb+1];
            float u2 = Fb[cb0+cb+2], u3 = Fb[cb0+cb+3];
            #pragma unroll
            for (int cp = 0; cp < 16; ++cp) {
                const float4 f = *(const float4*)&wlds[(cp << 9) + cb0 + cb];
                u0 = fmaf(tr[cp], f.x, u0);
                u1 = fmaf(tr[cp], f.y, u1);
                u2 = fmaf(tr[cp], f.z, u2);
                u3 = fmaf(tr[cp], f.w, u3);
            }
            acc = fmaf(xr[cb+0], u0, acc);
            acc = fmaf(xr[cb+1], u1, acc);
            acc = fmaf(xr[cb+2], u2, acc);
            acc = fmaf(xr[cb+3], u3, acc);
        }
        aF[tid * 17 + pp] = acc;
    }
    __syncthreads();                  // all F reads done -> re-stage W
    #pragma unroll
    for (int k = 0; k < 8192; k += 256) wlds[k + tid] = Ww[k + tid];

    // weight = aggr @ M_W + M_b (needs both halves; pair is in the same wave)
    float w = Mb[0];
    {
        const int base = (tid & ~1) * 17;
        #pragma unroll
        for (int q = 0; q < 32; ++q)
            w = fmaf(aF[base + (q >> 4) * 17 + (q & 15)], Mw[q], w);
    }
    __syncthreads();                  // W staged

    const int lane = tid & 63;
    // phase 2: + x^T (x^T W)_p, sigmoid, write conv, reduce S2
    #pragma unroll 1
    for (int pp = 0; pp < 16; ++pp) {
        const int cb0 = pbase + (pp << 4);
        float acc = 0.0f;
        #pragma unroll
        for (int cb = 0; cb < 16; cb += 4) {
            float u0 = Wb[cb0+cb+0], u1 = Wb[cb0+cb+1];
            float u2 = Wb[cb0+cb+2], u3 = Wb[cb0+cb+3];
            #pragma unroll
            for (int cp = 0; cp < 16; ++cp) {
                const float4 f = *(const float4*)&wlds[(cp << 9) + cb0 + cb];
                u0 = fmaf(xr[cp], f.x, u0);
                u1 = fmaf(xr[cp], f.y, u1);
                u2 = fmaf(xr[cp], f.z, u2);
                u3 = fmaf(xr[cp], f.w, u3);
            }
            acc = fmaf(xr[cb+0], u0, acc);
            acc = fmaf(xr[cb+1], u1, acc);
            acc = fmaf(xr[cb+2], u2, acc);
            acc = fmaf(xr[cb+3], u3, acc);
        }
        const float z  = aF[tid * 17 + pp] * w + acc + Bv[(h << 4) + pp];
        const float cv = 1.0f / (1.0f + expf(-z));
        conv[(size_t)i * 32 + (h << 4) + pp] = cv;
        // S2 partial: sum over same-parity lanes (same h -> same p)
        float v = cv;
        v += __shfl_xor(v, 2);
        v += __shfl_xor(v, 4);
        v += __shfl_xor(v, 8);
        v += __shfl_xor(v, 16);
        v += __shfl_xor(v, 32);
        if (lane < 2) atomicAdd(&S2s[n * 32 + (lane << 4) + pp], v);
    }
    // S1 partial: x sums (even lanes = each node once)
    #pragma unroll
    for (int c = 0; c < 16; ++c) {
        float v = xr[c];
        v += __shfl_xor(v, 2);
        v += __shfl_xor(v, 4);
        v += __shfl_xor(v, 8);
        v += __shfl_xor(v, 16);
        v += __shfl_xor(v, 32);
        if (lane == 0) atomicAdd(&S1s[n * 32 + c], v);
    }
}

// ---------------------------------------------------------------- gate
__global__ void gate_kernel(const float* __restrict__ S1s, const float* __restrict__ S2s,
    const float* __restrict__ m1W, const float* __restrict__ m1b,
    const float* __restrict__ m2W, const float* __restrict__ m2b,
    float* __restrict__ M0, float* __restrict__ M1, float invI)
{
    int t = threadIdx.x;              // N*32 threads
    int n = t >> 5, p = t & 31;
    float z1 = m1b[p], z2 = m2b[p];
    #pragma unroll
    for (int q = 0; q < 32; ++q) {
        z1 = fmaf(S1s[n * 32 + q] * invI, m1W[q * 32 + p], z1);
        z2 = fmaf(S2s[n * 32 + q] * invI, m2W[q * 32 + p], z2);
    }
    float m = fmaxf(z1, z2);
    float e1 = expf(z1 - m), e2 = expf(z2 - m);
    float inv = 1.0f / (e1 + e2);
    M0[t] = e1 * inv;
    M1[t] = e2 * inv;
}

// ---------------------------------------------------------------- fuse+pool
__global__ __launch_bounds__(256) void pool_kernel(
    const float* __restrict__ x, const float* __restrict__ conv,
    const int* __restrict__ cl, const float* __restrict__ M0,
    const float* __restrict__ M1, unsigned* __restrict__ pooledM)
{
    int i = blockIdx.x * 256 + threadIdx.x;
    int n = i >> 12;
    int c = cl[i];
    const float* m0 = M0 + n * 32;
    const float* m1 = M1 + n * 32;
    float cr[32];
    {
        const float4* q = (const float4*)(conv + (size_t)i * 32);
        #pragma unroll
        for (int b = 0; b < 8; ++b) {
            float4 v = q[b];
            cr[b*4+0] = v.x; cr[b*4+1] = v.y; cr[b*4+2] = v.z; cr[b*4+3] = v.w;
        }
    }
    float xr[16];
    load16(x + (size_t)i * 16, xr);
    unsigned* dstp = pooledM + (size_t)c * 32;
    #pragma unroll
    for (int p = 0; p < 32; ++p) {
        float xp = (p < 16) ? xr[p] : 0.0f;
        float f  = fmaf(m0[p], xp, m1[p] * cr[p]);
        atomicMax(&dstp[p], fmap(f));
    }
}

// ---------------------------------------------------------------- final
__global__ void final_kernel(const unsigned* __restrict__ pooledM,
    const float* __restrict__ scW, const float* __restrict__ scb,
    const float* __restrict__ lr, float* __restrict__ out, int total)
{
    int t = blockIdx.x * 256 + threadIdx.x;
    if (t >= total) return;
    int g = t >> 5, p = t & 31;
    float acc = scb[p];
    float self = 0.0f;
    #pragma unroll
    for (int q = 0; q < 32; ++q) {
        float v = funmap(pooledM[g * 32 + q]);
        if (q == p) self = v;
        acc = fmaf(v, scW[q * 32 + p], acc);
    }
    out[t] = self + lr[0] * acc;
}

extern "C" void kernel_launch(void* const* d_in, const int* in_sizes, int n_in,
                              void* d_out, int out_size, void* d_ws, size_t ws_size,
                              hipStream_t stream)
{
    const float* x   = (const float*)d_in[0];
    const int*   ei  = (const int*)d_in[1];
    const int*   clus= (const int*)d_in[2];
    const float* Fw  = (const float*)d_in[3];
    const float* Fb  = (const float*)d_in[4];
    const float* Ww  = (const float*)d_in[5];
    const float* Wb  = (const float*)d_in[6];
    const float* Mw  = (const float*)d_in[7];
    const float* Mb  = (const float*)d_in[8];
    const float* Bv  = (const float*)d_in[9];
    const float* m1W = (const float*)d_in[10];
    const float* m1b = (const float*)d_in[11];
    const float* m2W = (const float*)d_in[12];
    const float* m2b = (const float*)d_in[13];
    const float* scW = (const float*)d_in[14];
    const float* scb = (const float*)d_in[15];
    const float* lr  = (const float*)d_in[16];

    const int NI = in_sizes[0] / 16;   // 65536 nodes
    const int E  = in_sizes[1] / 2;    // 589824 edges
    const int nG = NI >> 12;           // clouds (I = 4096)
    const int nC = out_size / 32;      // clusters = K*N

    // ws layout (f32 elems): s[NI*16] | deg[NI] | S1s[nG*32] | S2s[nG*32] |
    //                        pooledM[nC*32 u32] | M0[nG*32] | M1[nG*32] | conv[NI*32]
    float* ws   = (float*)d_ws;
    float* s_   = ws;
    float* deg_ = s_ + (size_t)NI * 16;
    float* S1s  = deg_ + NI;
    float* S2s  = S1s + nG * 32;
    unsigned* pooledM = (unsigned*)(S2s + nG * 32);
    float* M0   = (float*)(pooledM + nC * 32);
    float* M1   = M0 + nG * 32;
    float* conv = M1 + nG * 32;

    // Defensive: if the harness workspace is smaller than this layout, do not
    // launch anything (a clean absmax failure is diagnosable; an OOB write that
    // kills the container is not).
    size_t need_bytes = (size_t)((char*)(conv + (size_t)NI * 32) - (char*)ws);
    if (ws_size < need_bytes) return;

    size_t zbytes = (size_t)((char*)(pooledM + nC * 32) - (char*)ws);
    hipMemsetAsync(d_ws, 0, zbytes, stream);   // zeros s, deg, S1s, S2s, pooledM(=-inf mapped)

    edge_scatter<<<dim3((E * 16 + 255) / 256), dim3(256), 0, stream>>>(x, ei, s_, deg_, E);
    node_update<<<dim3(NI * 2 / 256), dim3(256), 0, stream>>>(
        x, s_, deg_, Fw, Fb, Ww, Wb, Mw, Mb, Bv, conv, S1s, S2s);
    gate_kernel<<<dim3(1), dim3(nG * 32), 0, stream>>>(
        S1s, S2s, m1W, m1b, m2W, m2b, M0, M1, 1.0f / 4096.0f);
    pool_kernel<<<dim3(NI / 256), dim3(256), 0, stream>>>(x, conv, clus, M0, M1, pooledM);
    final_kernel<<<dim3((out_size + 255) / 256), dim3(256), 0, stream>>>(
        pooledM, scW, scb, lr, (float*)d_out, out_size);
}

// Round 11
// 310.901 us; speedup vs baseline: 1.4754x; 1.4754x over previous
//
#include <hip/hip_runtime.h>
#include <hip/hip_bf16.h>

// ShrinkingUnit: N=16, I=4096, C=16, P=16, K=8, CP=32, NI=65536.
// Math reduction: mean-aggregated bilinear message
//   aggr[i,p] = sum_c x_i[c] * (sum_c' tbar[c'] F_W[c',p*16+c] + F_b[p*16+c]),
//   tbar_i = s_i/deg_i - x_i,  s_i = sum of x_src over incoming edges.
// Pooling: hierarchical max (LDS table per block -> per-block tables in ws ->
// 32-way reduce), zero device-scope atomics. R8 post-mortem: direct global
// atomicMax on 4096 addresses from 65536 nodes = 512-way serialization,
// ~360 ns/op -> 186 us. LDS+reduce removes it.

#define POOL_NBLK 32

__device__ __forceinline__ unsigned fmap(float f) {
    unsigned u = __float_as_uint(f);
    return (u & 0x80000000u) ? ~u : (u | 0x80000000u);   // order-preserving map
}
__device__ __forceinline__ float funmap(unsigned m) {
    return (m & 0x80000000u) ? __uint_as_float(m & 0x7FFFFFFFu)
                             : __uint_as_float(~m);
}

__device__ __forceinline__ void load16(const float* __restrict__ p, float* r) {
    const float4* q = (const float4*)p;
    float4 a = q[0], b = q[1], c = q[2], d = q[3];
    r[0]=a.x; r[1]=a.y; r[2]=a.z; r[3]=a.w;
    r[4]=b.x; r[5]=b.y; r[6]=b.z; r[7]=b.w;
    r[8]=c.x; r[9]=c.y; r[10]=c.z; r[11]=c.w;
    r[12]=d.x; r[13]=d.y; r[14]=d.z; r[15]=d.w;
}

// ---------------------------------------------------------------- edges
__global__ __launch_bounds__(256) void edge_scatter(
    const float* __restrict__ x, const int* __restrict__ ei,
    float* __restrict__ s, float* __restrict__ deg, int E)
{
    int tid = blockIdx.x * 256 + threadIdx.x;
    int e = tid >> 4, c = tid & 15;
    if (e >= E) return;
    int src = ei[e];          // row 0 = src
    int dst = ei[E + e];      // row 1 = dst
    atomicAdd(&s[(size_t)dst * 16 + c], x[(size_t)src * 16 + c]);
    if (c == 0) atomicAdd(&deg[dst], 1.0f);
}

// ---------------------------------------------------------------- nodes
// 2 threads per node (each handles 16 of the 32 p's). Weights staged in LDS
// (F first, then re-staged as W). aF kept in padded LDS (stride 17) so loops
// stay rolled without scratch spills.
__global__ __launch_bounds__(256) void node_update(
    const float* __restrict__ x, const float* __restrict__ s,
    const float* __restrict__ deg,
    const float* __restrict__ Fw, const float* __restrict__ Fb,
    const float* __restrict__ Ww, const float* __restrict__ Wb,
    const float* __restrict__ Mw, const float* __restrict__ Mb,
    const float* __restrict__ Bv,
    float* __restrict__ conv, float* __restrict__ S1s, float* __restrict__ S2s)
{
    __shared__ float wlds[8192];      // 16 x 512 weight tile (F, then W)
    __shared__ float aF[256 * 17];    // per-thread 16 aF values, pad 17
    const int tid = threadIdx.x;
    #pragma unroll
    for (int k = 0; k < 8192; k += 256) wlds[k + tid] = Fw[k + tid];

    const int gt = blockIdx.x * 256 + tid;
    const int i  = gt >> 1;           // node
    const int h  = gt & 1;            // which 16-p half
    const int n  = i >> 12;           // cloud (I = 4096)

    float xr[16], tr[16];
    load16(x + (size_t)i * 16, xr);
    load16(s + (size_t)i * 16, tr);
    const float invd = 1.0f / deg[i];
    #pragma unroll
    for (int c = 0; c < 16; ++c) tr[c] = tr[c] * invd - xr[c];

    __syncthreads();                  // F staged

    const int pbase = h << 8;         // colBase = (h*16+pp)*16 = h*256 + pp*16
    // phase 1: aF[p] = x^T (tbar^T F)_p
    #pragma unroll 1
    for (int pp = 0; pp < 16; ++pp) {
        const int cb0 = pbase + (pp << 4);
        float acc = 0.0f;
        #pragma unroll
        for (int cb = 0; cb < 16; cb += 4) {
            float u0 = Fb[cb0+cb+0], u1 = Fb[cb0+cb+1];
            float u2 = Fb[cb0+cb+2], u3 = Fb[cb0+cb+3];
            #pragma unroll
            for (int cp = 0; cp < 16; ++cp) {
                const float4 f = *(const float4*)&wlds[(cp << 9) + cb0 + cb];
                u0 = fmaf(tr[cp], f.x, u0);
                u1 = fmaf(tr[cp], f.y, u1);
                u2 = fmaf(tr[cp], f.z, u2);
                u3 = fmaf(tr[cp], f.w, u3);
            }
            acc = fmaf(xr[cb+0], u0, acc);
            acc = fmaf(xr[cb+1], u1, acc);
            acc = fmaf(xr[cb+2], u2, acc);
            acc = fmaf(xr[cb+3], u3, acc);
        }
        aF[tid * 17 + pp] = acc;
    }
    __syncthreads();                  // all F reads done -> re-stage W
    #pragma unroll
    for (int k = 0; k < 8192; k += 256) wlds[k + tid] = Ww[k + tid];

    // weight = aggr @ M_W + M_b (needs both halves; pair is in the same wave)
    float w = Mb[0];
    {
        const int base = (tid & ~1) * 17;
        #pragma unroll
        for (int q = 0; q < 32; ++q)
            w = fmaf(aF[base + (q >> 4) * 17 + (q & 15)], Mw[q], w);
    }
    __syncthreads();                  // W staged

    const int lane = tid & 63;
    // phase 2: + x^T (x^T W)_p, sigmoid, write conv, reduce S2
    #pragma unroll 1
    for (int pp = 0; pp < 16; ++pp) {
        const int cb0 = pbase + (pp << 4);
        float acc = 0.0f;
        #pragma unroll
        for (int cb = 0; cb < 16; cb += 4) {
            float u0 = Wb[cb0+cb+0], u1 = Wb[cb0+cb+1];
            float u2 = Wb[cb0+cb+2], u3 = Wb[cb0+cb+3];
            #pragma unroll
            for (int cp = 0; cp < 16; ++cp) {
                const float4 f = *(const float4*)&wlds[(cp << 9) + cb0 + cb];
                u0 = fmaf(xr[cp], f.x, u0);
                u1 = fmaf(xr[cp], f.y, u1);
                u2 = fmaf(xr[cp], f.z, u2);
                u3 = fmaf(xr[cp], f.w, u3);
            }
            acc = fmaf(xr[cb+0], u0, acc);
            acc = fmaf(xr[cb+1], u1, acc);
            acc = fmaf(xr[cb+2], u2, acc);
            acc = fmaf(xr[cb+3], u3, acc);
        }
        const float z  = aF[tid * 17 + pp] * w + acc + Bv[(h << 4) + pp];
        const float cv = 1.0f / (1.0f + expf(-z));
        conv[(size_t)i * 32 + (h << 4) + pp] = cv;
        // S2 partial: sum over same-parity lanes (same h -> same p)
        float v = cv;
        v += __shfl_xor(v, 2);
        v += __shfl_xor(v, 4);
        v += __shfl_xor(v, 8);
        v += __shfl_xor(v, 16);
        v += __shfl_xor(v, 32);
        if (lane < 2) atomicAdd(&S2s[n * 32 + (lane << 4) + pp], v);
    }
    // S1 partial: x sums (even lanes = each node once)
    #pragma unroll
    for (int c = 0; c < 16; ++c) {
        float v = xr[c];
        v += __shfl_xor(v, 2);
        v += __shfl_xor(v, 4);
        v += __shfl_xor(v, 8);
        v += __shfl_xor(v, 16);
        v += __shfl_xor(v, 32);
        if (lane == 0) atomicAdd(&S1s[n * 32 + c], v);
    }
}

// ---------------------------------------------------------------- gate
__global__ void gate_kernel(const float* __restrict__ S1s, const float* __restrict__ S2s,
    const float* __restrict__ m1W, const float* __restrict__ m1b,
    const float* __restrict__ m2W, const float* __restrict__ m2b,
    float* __restrict__ M0, float* __restrict__ M1, float invI)
{
    int t = threadIdx.x;              // N*32 threads
    int n = t >> 5, p = t & 31;
    float z1 = m1b[p], z2 = m2b[p];
    #pragma unroll
    for (int q = 0; q < 32; ++q) {
        z1 = fmaf(S1s[n * 32 + q] * invI, m1W[q * 32 + p], z1);
        z2 = fmaf(S2s[n * 32 + q] * invI, m2W[q * 32 + p], z2);
    }
    float m = fmaxf(z1, z2);
    float e1 = expf(z1 - m), e2 = expf(z2 - m);
    float inv = 1.0f / (e1 + e2);
    M0[t] = e1 * inv;
    M1[t] = e2 * inv;
}

// ---------------------------------------------------------------- fuse+pool
// Grid-stride over nodes; per-block LDS max-table (nC*32 slots, u32 fmap
// space, 0 == -inf sentinel); block table stored to blkT (reused s_ buffer).
__global__ __launch_bounds__(256) void pool_kernel(
    const float* __restrict__ x, const float* __restrict__ conv,
    const int* __restrict__ cl, const float* __restrict__ M0,
    const float* __restrict__ M1, unsigned* __restrict__ blkT,
    int NI, int nSlots)
{
    __shared__ unsigned utab[4096];   // nC*32 <= 4096 (nC = 128 here)
    const int tid = threadIdx.x;
    for (int t = tid; t < nSlots; t += 256) utab[t] = 0u;
    __syncthreads();

    for (int i = blockIdx.x * 256 + tid; i < NI; i += POOL_NBLK * 256) {
        int n = i >> 12;
        int c = cl[i];
        const float* m0 = M0 + n * 32;
        const float* m1 = M1 + n * 32;
        float cr[32];
        {
            const float4* q = (const float4*)(conv + (size_t)i * 32);
            #pragma unroll
            for (int b = 0; b < 8; ++b) {
                float4 v = q[b];
                cr[b*4+0] = v.x; cr[b*4+1] = v.y; cr[b*4+2] = v.z; cr[b*4+3] = v.w;
            }
        }
        float xr[16];
        load16(x + (size_t)i * 16, xr);
        unsigned* up = utab + (c << 5);
        #pragma unroll
        for (int p = 0; p < 16; ++p) {
            float f = fmaf(m0[p], xr[p], m1[p] * cr[p]);
            atomicMax(&up[p], fmap(f));
        }
        #pragma unroll
        for (int p = 16; p < 32; ++p) {
            float f = m1[p] * cr[p];   // x_pad is zero for p >= 16
            atomicMax(&up[p], fmap(f));
        }
    }
    __syncthreads();
    unsigned* dst = blkT + (size_t)blockIdx.x * nSlots;
    for (int t = tid; t < nSlots; t += 256) dst[t] = utab[t];
}

__global__ __launch_bounds__(256) void pool_reduce(
    const unsigned* __restrict__ blkT, unsigned* __restrict__ pooledM, int nSlots)
{
    int t = blockIdx.x * 256 + threadIdx.x;
    if (t >= nSlots) return;
    unsigned m = 0u;
    #pragma unroll
    for (int b = 0; b < POOL_NBLK; ++b)
        m = max(m, blkT[(size_t)b * nSlots + t]);
    pooledM[t] = m;
}

// ---------------------------------------------------------------- final
__global__ void final_kernel(const unsigned* __restrict__ pooledM,
    const float* __restrict__ scW, const float* __restrict__ scb,
    const float* __restrict__ lr, float* __restrict__ out, int total)
{
    int t = blockIdx.x * 256 + threadIdx.x;
    if (t >= total) return;
    int g = t >> 5, p = t & 31;
    float acc = scb[p];
    float self = 0.0f;
    #pragma unroll
    for (int q = 0; q < 32; ++q) {
        float v = funmap(pooledM[g * 32 + q]);
        if (q == p) self = v;
        acc = fmaf(v, scW[q * 32 + p], acc);
    }
    out[t] = self + lr[0] * acc;
}

extern "C" void kernel_launch(void* const* d_in, const int* in_sizes, int n_in,
                              void* d_out, int out_size, void* d_ws, size_t ws_size,
                              hipStream_t stream)
{
    const float* x   = (const float*)d_in[0];
    const int*   ei  = (const int*)d_in[1];
    const int*   clus= (const int*)d_in[2];
    const float* Fw  = (const float*)d_in[3];
    const float* Fb  = (const float*)d_in[4];
    const float* Ww  = (const float*)d_in[5];
    const float* Wb  = (const float*)d_in[6];
    const float* Mw  = (const float*)d_in[7];
    const float* Mb  = (const float*)d_in[8];
    const float* Bv  = (const float*)d_in[9];
    const float* m1W = (const float*)d_in[10];
    const float* m1b = (const float*)d_in[11];
    const float* m2W = (const float*)d_in[12];
    const float* m2b = (const float*)d_in[13];
    const float* scW = (const float*)d_in[14];
    const float* scb = (const float*)d_in[15];
    const float* lr  = (const float*)d_in[16];

    const int NI = in_sizes[0] / 16;   // 65536 nodes
    const int E  = in_sizes[1] / 2;    // 589824 edges
    const int nG = NI >> 12;           // clouds (I = 4096)
    const int nC = out_size / 32;      // clusters = K*N
    const int nSlots = nC * 32;        // 4096

    // ws layout (f32 elems): s[NI*16] | deg[NI] | S1s[nG*32] | S2s[nG*32] |
    //                        pooledM[nC*32 u32] | M0[nG*32] | M1[nG*32] | conv[NI*32]
    // s_ (4 MB) is dead after node_update -> reused as blkT (POOL_NBLK tables).
    float* ws   = (float*)d_ws;
    float* s_   = ws;
    float* deg_ = s_ + (size_t)NI * 16;
    float* S1s  = deg_ + NI;
    float* S2s  = S1s + nG * 32;
    unsigned* pooledM = (unsigned*)(S2s + nG * 32);
    float* M0   = (float*)(pooledM + nSlots);
    float* M1   = M0 + nG * 32;
    float* conv = M1 + nG * 32;
    unsigned* blkT = (unsigned*)s_;    // POOL_NBLK * nSlots u32 = 512 KB << 4 MB

    // Defensive: if the harness workspace is smaller than this layout, do not
    // launch anything (a clean absmax failure is diagnosable; an OOB write that
    // kills the container is not).
    size_t need_bytes = (size_t)((char*)(conv + (size_t)NI * 32) - (char*)ws);
    if (ws_size < need_bytes || nSlots > 4096) return;

    size_t zbytes = (size_t)((char*)(pooledM + nSlots) - (char*)ws);
    hipMemsetAsync(d_ws, 0, zbytes, stream);   // zeros s, deg, S1s, S2s, pooledM

    edge_scatter<<<dim3((E * 16 + 255) / 256), dim3(256), 0, stream>>>(x, ei, s_, deg_, E);
    node_update<<<dim3(NI * 2 / 256), dim3(256), 0, stream>>>(
        x, s_, deg_, Fw, Fb, Ww, Wb, Mw, Mb, Bv, conv, S1s, S2s);
    gate_kernel<<<dim3(1), dim3(nG * 32), 0, stream>>>(
        S1s, S2s, m1W, m1b, m2W, m2b, M0, M1, 1.0f / 4096.0f);
    pool_kernel<<<dim3(POOL_NBLK), dim3(256), 0, stream>>>(
        x, conv, clus, M0, M1, blkT, NI, nSlots);
    pool_reduce<<<dim3((nSlots + 255) / 256), dim3(256), 0, stream>>>(
        blkT, pooledM, nSlots);
    final_kernel<<<dim3((out_size + 255) / 256), dim3(256), 0, stream>>>(
        pooledM, scW, scb, lr, (float*)d_out, out_size);
}

// Round 12
// 276.827 us; speedup vs baseline: 1.6570x; 1.1231x over previous
//
#include <hip/hip_runtime.h>
#include <hip/hip_bf16.h>

// ShrinkingUnit: N=16, I=4096, C=16, P=16, K=8, CP=32, NI=65536.
// Math reduction: mean-aggregated bilinear message
//   aggr[i,p] = sum_c x_i[c] * (sum_c' tbar[c'] F_W[c',p*16+c] + F_b[p*16+c]),
//   tbar_i = s_i/deg_i - x_i,  s_i = sum of x_src over incoming edges.
// R11 post-mortem: node_update had 16.8M LDS bank-conflict cycles because h
// alternated per-lane -> each wave read 2 distinct wlds addresses 256 floats
// apart (same 4-bank group) -> ~16-way serialization. Fix: h is wave-uniform
// (wave w: h=w&1, nodes=(w>>1)*64+lane) -> all 64 lanes read the SAME address
// -> broadcast, zero conflict.
// Pooling: hierarchical LDS max tables (R8: global atomicMax was 512-way
// serialized, 186us).

#define POOL_NBLK 32

__device__ __forceinline__ unsigned fmap(float f) {
    unsigned u = __float_as_uint(f);
    return (u & 0x80000000u) ? ~u : (u | 0x80000000u);   // order-preserving map
}
__device__ __forceinline__ float funmap(unsigned m) {
    return (m & 0x80000000u) ? __uint_as_float(m & 0x7FFFFFFFu)
                             : __uint_as_float(~m);
}

__device__ __forceinline__ void load16(const float* __restrict__ p, float* r) {
    const float4* q = (const float4*)p;
    float4 a = q[0], b = q[1], c = q[2], d = q[3];
    r[0]=a.x; r[1]=a.y; r[2]=a.z; r[3]=a.w;
    r[4]=b.x; r[5]=b.y; r[6]=b.z; r[7]=b.w;
    r[8]=c.x; r[9]=c.y; r[10]=c.z; r[11]=c.w;
    r[12]=d.x; r[13]=d.y; r[14]=d.z; r[15]=d.w;
}

// ---------------------------------------------------------------- edges
__global__ __launch_bounds__(256) void edge_scatter(
    const float* __restrict__ x, const int* __restrict__ ei,
    float* __restrict__ s, float* __restrict__ deg, int E)
{
    int tid = blockIdx.x * 256 + threadIdx.x;
    int e = tid >> 4, c = tid & 15;
    if (e >= E) return;
    int src = ei[e];          // row 0 = src
    int dst = ei[E + e];      // row 1 = dst
    atomicAdd(&s[(size_t)dst * 16 + c], x[(size_t)src * 16 + c]);
    if (c == 0) atomicAdd(&deg[dst], 1.0f);
}

// ---------------------------------------------------------------- nodes
// Wave-uniform h: wave w of each block handles half h=w&1 for nodes
// blk*128 + (w>>1)*64 + lane. Weight reads are wave-uniform -> LDS broadcast.
__global__ __launch_bounds__(256) void node_update(
    const float* __restrict__ x, const float* __restrict__ s,
    const float* __restrict__ deg,
    const float* __restrict__ Fw, const float* __restrict__ Fb,
    const float* __restrict__ Ww, const float* __restrict__ Wb,
    const float* __restrict__ Mw, const float* __restrict__ Mb,
    const float* __restrict__ Bv,
    float* __restrict__ conv, float* __restrict__ S1s, float* __restrict__ S2s)
{
    __shared__ float wlds[8192];      // 16 x 512 weight tile (F, then W)
    __shared__ float aF[256 * 17];    // per-thread 16 aF values, pad 17
    const int tid = threadIdx.x;
    #pragma unroll
    for (int k = 0; k < 8192; k += 256) wlds[k + tid] = Fw[k + tid];

    const int lane = tid & 63;
    const int w4   = tid >> 6;                            // wave 0..3
    const int h    = w4 & 1;                              // wave-uniform half
    const int i    = blockIdx.x * 128 + ((w4 >> 1) << 6) + lane;  // node
    const int n    = i >> 12;                             // cloud (I = 4096)

    float xr[16], tr[16];
    load16(x + (size_t)i * 16, xr);
    load16(s + (size_t)i * 16, tr);
    const float invd = 1.0f / deg[i];
    #pragma unroll
    for (int c = 0; c < 16; ++c) tr[c] = tr[c] * invd - xr[c];

    __syncthreads();                  // F staged

    const int pbase = h << 8;         // colBase = (h*16+pp)*16 = h*256 + pp*16
    // phase 1: aF[p] = x^T (tbar^T F)_p
    #pragma unroll 1
    for (int pp = 0; pp < 16; ++pp) {
        const int cb0 = pbase + (pp << 4);
        float acc = 0.0f;
        #pragma unroll
        for (int cb = 0; cb < 16; cb += 4) {
            float u0 = Fb[cb0+cb+0], u1 = Fb[cb0+cb+1];
            float u2 = Fb[cb0+cb+2], u3 = Fb[cb0+cb+3];
            #pragma unroll
            for (int cp = 0; cp < 16; ++cp) {
                const float4 f = *(const float4*)&wlds[(cp << 9) + cb0 + cb];
                u0 = fmaf(tr[cp], f.x, u0);
                u1 = fmaf(tr[cp], f.y, u1);
                u2 = fmaf(tr[cp], f.z, u2);
                u3 = fmaf(tr[cp], f.w, u3);
            }
            acc = fmaf(xr[cb+0], u0, acc);
            acc = fmaf(xr[cb+1], u1, acc);
            acc = fmaf(xr[cb+2], u2, acc);
            acc = fmaf(xr[cb+3], u3, acc);
        }
        aF[tid * 17 + pp] = acc;
    }
    __syncthreads();                  // all F reads done -> re-stage W
    #pragma unroll
    for (int k = 0; k < 8192; k += 256) wlds[k + tid] = Ww[k + tid];

    // weight = aggr @ M_W + M_b; partner row (other h) is tid^64
    float w = Mb[0];
    {
        const int base0 = (tid & ~64) * 17;   // h=0 row of this node
        const int base1 = base0 + 64 * 17;    // h=1 row
        #pragma unroll
        for (int q = 0; q < 16; ++q) w = fmaf(aF[base0 + q], Mw[q], w);
        #pragma unroll
        for (int q = 0; q < 16; ++q) w = fmaf(aF[base1 + q], Mw[16 + q], w);
    }
    __syncthreads();                  // W staged

    // phase 2: + x^T (x^T W)_p, sigmoid, write conv, reduce S2
    #pragma unroll 1
    for (int pp = 0; pp < 16; ++pp) {
        const int cb0 = pbase + (pp << 4);
        float acc = 0.0f;
        #pragma unroll
        for (int cb = 0; cb < 16; cb += 4) {
            float u0 = Wb[cb0+cb+0], u1 = Wb[cb0+cb+1];
            float u2 = Wb[cb0+cb+2], u3 = Wb[cb0+cb+3];
            #pragma unroll
            for (int cp = 0; cp < 16; ++cp) {
                const float4 f = *(const float4*)&wlds[(cp << 9) + cb0 + cb];
                u0 = fmaf(xr[cp], f.x, u0);
                u1 = fmaf(xr[cp], f.y, u1);
                u2 = fmaf(xr[cp], f.z, u2);
                u3 = fmaf(xr[cp], f.w, u3);
            }
            acc = fmaf(xr[cb+0], u0, acc);
            acc = fmaf(xr[cb+1], u1, acc);
            acc = fmaf(xr[cb+2], u2, acc);
            acc = fmaf(xr[cb+3], u3, acc);
        }
        const float z  = aF[tid * 17 + pp] * w + acc + Bv[(h << 4) + pp];
        const float cv = 1.0f / (1.0f + expf(-z));
        conv[(size_t)i * 32 + (h << 4) + pp] = cv;
        // S2 partial: full-wave sum (whole wave shares h and pp)
        float v = cv;
        v += __shfl_xor(v, 1);
        v += __shfl_xor(v, 2);
        v += __shfl_xor(v, 4);
        v += __shfl_xor(v, 8);
        v += __shfl_xor(v, 16);
        v += __shfl_xor(v, 32);
        if (lane == 0) atomicAdd(&S2s[n * 32 + (h << 4) + pp], v);
    }
    // S1 partial: x sums — h==0 waves cover each node exactly once
    if (h == 0) {
        #pragma unroll
        for (int c = 0; c < 16; ++c) {
            float v = xr[c];
            v += __shfl_xor(v, 1);
            v += __shfl_xor(v, 2);
            v += __shfl_xor(v, 4);
            v += __shfl_xor(v, 8);
            v += __shfl_xor(v, 16);
            v += __shfl_xor(v, 32);
            if (lane == 0) atomicAdd(&S1s[n * 32 + c], v);
        }
    }
}

// ---------------------------------------------------------------- gate
__global__ void gate_kernel(const float* __restrict__ S1s, const float* __restrict__ S2s,
    const float* __restrict__ m1W, const float* __restrict__ m1b,
    const float* __restrict__ m2W, const float* __restrict__ m2b,
    float* __restrict__ M0, float* __restrict__ M1, float invI)
{
    int t = threadIdx.x;              // N*32 threads
    int n = t >> 5, p = t & 31;
    float z1 = m1b[p], z2 = m2b[p];
    #pragma unroll
    for (int q = 0; q < 32; ++q) {
        z1 = fmaf(S1s[n * 32 + q] * invI, m1W[q * 32 + p], z1);
        z2 = fmaf(S2s[n * 32 + q] * invI, m2W[q * 32 + p], z2);
    }
    float m = fmaxf(z1, z2);
    float e1 = expf(z1 - m), e2 = expf(z2 - m);
    float inv = 1.0f / (e1 + e2);
    M0[t] = e1 * inv;
    M1[t] = e2 * inv;
}

// ---------------------------------------------------------------- fuse+pool
// Grid-stride over nodes; per-block LDS max-table (nC*32 slots, u32 fmap
// space, 0 == -inf sentinel); block table stored to blkT (reused s_ buffer).
__global__ __launch_bounds__(256) void pool_kernel(
    const float* __restrict__ x, const float* __restrict__ conv,
    const int* __restrict__ cl, const float* __restrict__ M0,
    const float* __restrict__ M1, unsigned* __restrict__ blkT,
    int NI, int nSlots)
{
    __shared__ unsigned utab[4096];   // nC*32 <= 4096 (nC = 128 here)
    const int tid = threadIdx.x;
    for (int t = tid; t < nSlots; t += 256) utab[t] = 0u;
    __syncthreads();

    for (int i = blockIdx.x * 256 + tid; i < NI; i += POOL_NBLK * 256) {
        int n = i >> 12;
        int c = cl[i];
        const float* m0 = M0 + n * 32;
        const float* m1 = M1 + n * 32;
        float cr[32];
        {
            const float4* q = (const float4*)(conv + (size_t)i * 32);
            #pragma unroll
            for (int b = 0; b < 8; ++b) {
                float4 v = q[b];
                cr[b*4+0] = v.x; cr[b*4+1] = v.y; cr[b*4+2] = v.z; cr[b*4+3] = v.w;
            }
        }
        float xr[16];
        load16(x + (size_t)i * 16, xr);
        unsigned* up = utab + (c << 5);
        #pragma unroll
        for (int p = 0; p < 16; ++p) {
            float f = fmaf(m0[p], xr[p], m1[p] * cr[p]);
            atomicMax(&up[p], fmap(f));
        }
        #pragma unroll
        for (int p = 16; p < 32; ++p) {
            float f = m1[p] * cr[p];   // x_pad is zero for p >= 16
            atomicMax(&up[p], fmap(f));
        }
    }
    __syncthreads();
    unsigned* dst = blkT + (size_t)blockIdx.x * nSlots;
    for (int t = tid; t < nSlots; t += 256) dst[t] = utab[t];
}

__global__ __launch_bounds__(256) void pool_reduce(
    const unsigned* __restrict__ blkT, unsigned* __restrict__ pooledM, int nSlots)
{
    int t = blockIdx.x * 256 + threadIdx.x;
    if (t >= nSlots) return;
    unsigned m = 0u;
    #pragma unroll
    for (int b = 0; b < POOL_NBLK; ++b)
        m = max(m, blkT[(size_t)b * nSlots + t]);
    pooledM[t] = m;
}

// ---------------------------------------------------------------- final
__global__ void final_kernel(const unsigned* __restrict__ pooledM,
    const float* __restrict__ scW, const float* __restrict__ scb,
    const float* __restrict__ lr, float* __restrict__ out, int total)
{
    int t = blockIdx.x * 256 + threadIdx.x;
    if (t >= total) return;
    int g = t >> 5, p = t & 31;
    float acc = scb[p];
    float self = 0.0f;
    #pragma unroll
    for (int q = 0; q < 32; ++q) {
        float v = funmap(pooledM[g * 32 + q]);
        if (q == p) self = v;
        acc = fmaf(v, scW[q * 32 + p], acc);
    }
    out[t] = self + lr[0] * acc;
}

extern "C" void kernel_launch(void* const* d_in, const int* in_sizes, int n_in,
                              void* d_out, int out_size, void* d_ws, size_t ws_size,
                              hipStream_t stream)
{
    const float* x   = (const float*)d_in[0];
    const int*   ei  = (const int*)d_in[1];
    const int*   clus= (const int*)d_in[2];
    const float* Fw  = (const float*)d_in[3];
    const float* Fb  = (const float*)d_in[4];
    const float* Ww  = (const float*)d_in[5];
    const float* Wb  = (const float*)d_in[6];
    const float* Mw  = (const float*)d_in[7];
    const float* Mb  = (const float*)d_in[8];
    const float* Bv  = (const float*)d_in[9];
    const float* m1W = (const float*)d_in[10];
    const float* m1b = (const float*)d_in[11];
    const float* m2W = (const float*)d_in[12];
    const float* m2b = (const float*)d_in[13];
    const float* scW = (const float*)d_in[14];
    const float* scb = (const float*)d_in[15];
    const float* lr  = (const float*)d_in[16];

    const int NI = in_sizes[0] / 16;   // 65536 nodes
    const int E  = in_sizes[1] / 2;    // 589824 edges
    const int nG = NI >> 12;           // clouds (I = 4096)
    const int nC = out_size / 32;      // clusters = K*N
    const int nSlots = nC * 32;        // 4096

    // ws layout (f32 elems): s[NI*16] | deg[NI] | S1s[nG*32] | S2s[nG*32] |
    //                        pooledM[nC*32 u32] | M0[nG*32] | M1[nG*32] | conv[NI*32]
    // s_ (4 MB) is dead after node_update -> reused as blkT (POOL_NBLK tables).
    float* ws   = (float*)d_ws;
    float* s_   = ws;
    float* deg_ = s_ + (size_t)NI * 16;
    float* S1s  = deg_ + NI;
    float* S2s  = S1s + nG * 32;
    unsigned* pooledM = (unsigned*)(S2s + nG * 32);
    float* M0   = (float*)(pooledM + nSlots);
    float* M1   = M0 + nG * 32;
    float* conv = M1 + nG * 32;
    unsigned* blkT = (unsigned*)s_;    // POOL_NBLK * nSlots u32 = 512 KB << 4 MB

    // Defensive: if the harness workspace is smaller than this layout, do not
    // launch anything (a clean absmax failure is diagnosable; an OOB write that
    // kills the container is not).
    size_t need_bytes = (size_t)((char*)(conv + (size_t)NI * 32) - (char*)ws);
    if (ws_size < need_bytes || nSlots > 4096) return;

    size_t zbytes = (size_t)((char*)(pooledM + nSlots) - (char*)ws);
    hipMemsetAsync(d_ws, 0, zbytes, stream);   // zeros s, deg, S1s, S2s, pooledM

    edge_scatter<<<dim3((E * 16 + 255) / 256), dim3(256), 0, stream>>>(x, ei, s_, deg_, E);
    node_update<<<dim3(NI * 2 / 256), dim3(256), 0, stream>>>(
        x, s_, deg_, Fw, Fb, Ww, Wb, Mw, Mb, Bv, conv, S1s, S2s);
    gate_kernel<<<dim3(1), dim3(nG * 32), 0, stream>>>(
        S1s, S2s, m1W, m1b, m2W, m2b, M0, M1, 1.0f / 4096.0f);
    pool_kernel<<<dim3(POOL_NBLK), dim3(256), 0, stream>>>(
        x, conv, clus, M0, M1, blkT, NI, nSlots);
    pool_reduce<<<dim3((nSlots + 255) / 256), dim3(256), 0, stream>>>(
        blkT, pooledM, nSlots);
    final_kernel<<<dim3((out_size + 255) / 256), dim3(256), 0, stream>>>(
        pooledM, scW, scb, lr, (float*)d_out, out_size);
}

// Round 15
// 268.645 us; speedup vs baseline: 1.7075x; 1.0305x over previous
//
#include <hip/hip_runtime.h>
#include <hip/hip_bf16.h>

// ShrinkingUnit: N=16, I=4096, C=16, P=16, K=8, CP=32, NI=65536.
// aggr[i,p] = sum_c x_i[c]*(sum_c' tbar[c'] F_W[c',p*16+c] + F_b[p*16+c]),
//   tbar_i = s_i/deg_i - x_i.
// R11: bank conflicts (16.8M cyc) -> wave-uniform h fixed it (R12: 0 conflicts).
// R12: still 91us -- LDS-ISSUE bound: 2048 waves x 2048 ds_read_b128 x 12cyc
//   = 82us/CU model matches. Fix: NB=2 node register blocking -> each b128
//   feeds 8 FMAs, wave-level LDS instrs halve -> predict ~45us.
// Pool: hierarchical LDS tables (R8: global atomicMax 512-way serial = 186us);
//   POOL_NBLK 32->256 (was using 12.5% of CUs).

#define POOL_NBLK 256

__device__ __forceinline__ unsigned fmap(float f) {
    unsigned u = __float_as_uint(f);
    return (u & 0x80000000u) ? ~u : (u | 0x80000000u);   // order-preserving map
}
__device__ __forceinline__ float funmap(unsigned m) {
    return (m & 0x80000000u) ? __uint_as_float(m & 0x7FFFFFFFu)
                             : __uint_as_float(~m);
}

__device__ __forceinline__ void load16(const float* __restrict__ p, float* r) {
    const float4* q = (const float4*)p;
    float4 a = q[0], b = q[1], c = q[2], d = q[3];
    r[0]=a.x; r[1]=a.y; r[2]=a.z; r[3]=a.w;
    r[4]=b.x; r[5]=b.y; r[6]=b.z; r[7]=b.w;
    r[8]=c.x; r[9]=c.y; r[10]=c.z; r[11]=c.w;
    r[12]=d.x; r[13]=d.y; r[14]=d.z; r[15]=d.w;
}

// ---------------------------------------------------------------- edges
__global__ __launch_bounds__(256) void edge_scatter(
    const float* __restrict__ x, const int* __restrict__ ei,
    float* __restrict__ s, float* __restrict__ deg, int E)
{
    int tid = blockIdx.x * 256 + threadIdx.x;
    int e = tid >> 4, c = tid & 15;
    if (e >= E) return;
    int src = ei[e];          // row 0 = src
    int dst = ei[E + e];      // row 1 = dst
    atomicAdd(&s[(size_t)dst * 16 + c], x[(size_t)src * 16 + c]);
    if (c == 0) atomicAdd(&deg[dst], 1.0f);
}

// ---------------------------------------------------------------- nodes
// 128 threads = 2 waves (wave = h, wave-uniform -> LDS broadcast, 0 conflicts).
// NB=2: thread handles nodes i0 = blk*128+lane and i1 = i0+64 -> each weight
// b128 read feeds 8 FMAs. aF rows: [tid*34 + nb*17 + pp].
__global__ __launch_bounds__(128) void node_update(
    const float* __restrict__ x, const float* __restrict__ s,
    const float* __restrict__ deg,
    const float* __restrict__ Fw, const float* __restrict__ Fb,
    const float* __restrict__ Ww, const float* __restrict__ Wb,
    const float* __restrict__ Mw, const float* __restrict__ Mb,
    const float* __restrict__ Bv,
    float* __restrict__ conv, float* __restrict__ S1s, float* __restrict__ S2s)
{
    __shared__ float wlds[8192];      // 16 x 512 weight tile (F, then W)
    __shared__ float aF[128 * 34];    // 2 nodes x 16 aF per thread, pad 17
    const int tid = threadIdx.x;

    {   // stage F, vectorized: 2048 float4 / 128 threads = 16 each
        const float4* F4 = (const float4*)Fw;
        float4* w4 = (float4*)wlds;
        #pragma unroll
        for (int k = 0; k < 16; ++k) w4[k * 128 + tid] = F4[k * 128 + tid];
    }

    const int lane = tid & 63;
    const int h    = tid >> 6;                 // wave-uniform half
    const int i0   = blockIdx.x * 128 + lane;  // node A
    const int i1   = i0 + 64;                  // node B
    const int n    = i0 >> 12;                 // cloud (I=4096; 128 | 4096)

    float xr0[16], tr0[16], xr1[16], tr1[16];
    load16(x + (size_t)i0 * 16, xr0);
    load16(s + (size_t)i0 * 16, tr0);
    load16(x + (size_t)i1 * 16, xr1);
    load16(s + (size_t)i1 * 16, tr1);
    const float invd0 = 1.0f / deg[i0];
    const float invd1 = 1.0f / deg[i1];
    #pragma unroll
    for (int c = 0; c < 16; ++c) {
        tr0[c] = tr0[c] * invd0 - xr0[c];
        tr1[c] = tr1[c] * invd1 - xr1[c];
    }

    __syncthreads();                  // F staged

    const int pbase = h << 8;
    // phase 1: aF[nb][p] = x^T (tbar^T F)_p
    #pragma unroll 1
    for (int pp = 0; pp < 16; ++pp) {
        const int cb0 = pbase + (pp << 4);
        float acc0 = 0.0f, acc1 = 0.0f;
        #pragma unroll
        for (int cb = 0; cb < 16; cb += 4) {
            const float b0 = Fb[cb0+cb+0], b1 = Fb[cb0+cb+1];
            const float b2 = Fb[cb0+cb+2], b3 = Fb[cb0+cb+3];
            float u00=b0,u01=b1,u02=b2,u03=b3;
            float u10=b0,u11=b1,u12=b2,u13=b3;
            #pragma unroll
            for (int cp = 0; cp < 16; ++cp) {
                const float4 f = *(const float4*)&wlds[(cp << 9) + cb0 + cb];
                u00 = fmaf(tr0[cp], f.x, u00);
                u01 = fmaf(tr0[cp], f.y, u01);
                u02 = fmaf(tr0[cp], f.z, u02);
                u03 = fmaf(tr0[cp], f.w, u03);
                u10 = fmaf(tr1[cp], f.x, u10);
                u11 = fmaf(tr1[cp], f.y, u11);
                u12 = fmaf(tr1[cp], f.z, u12);
                u13 = fmaf(tr1[cp], f.w, u13);
            }
            acc0 = fmaf(xr0[cb+0], u00, acc0);
            acc0 = fmaf(xr0[cb+1], u01, acc0);
            acc0 = fmaf(xr0[cb+2], u02, acc0);
            acc0 = fmaf(xr0[cb+3], u03, acc0);
            acc1 = fmaf(xr1[cb+0], u10, acc1);
            acc1 = fmaf(xr1[cb+1], u11, acc1);
            acc1 = fmaf(xr1[cb+2], u12, acc1);
            acc1 = fmaf(xr1[cb+3], u13, acc1);
        }
        aF[tid * 34 + pp]      = acc0;
        aF[tid * 34 + 17 + pp] = acc1;
    }
    __syncthreads();                  // all F reads + aF writes done
    {   // re-stage W
        const float4* W4 = (const float4*)Ww;
        float4* w4 = (float4*)wlds;
        #pragma unroll
        for (int k = 0; k < 16; ++k) w4[k * 128 + tid] = W4[k * 128 + tid];
    }

    // weight = aggr @ M_W + M_b; rows: wave0 = lane*34, wave1 = (64+lane)*34
    float wgt0 = Mb[0], wgt1 = Mb[0];
    {
        const int r0 = lane * 34;          // h=0 rows (nodes i0,i1)
        const int r1 = (64 + lane) * 34;   // h=1 rows
        #pragma unroll
        for (int q = 0; q < 16; ++q) {
            wgt0 = fmaf(aF[r0 + q],      Mw[q],      wgt0);
            wgt0 = fmaf(aF[r1 + q],      Mw[16 + q], wgt0);
            wgt1 = fmaf(aF[r0 + 17 + q], Mw[q],      wgt1);
            wgt1 = fmaf(aF[r1 + 17 + q], Mw[16 + q], wgt1);
        }
    }
    __syncthreads();                  // W staged; aF M-reads done

    // phase 2: + x^T (x^T W)_p, sigmoid, conv, S2 reduce
    #pragma unroll 1
    for (int pp = 0; pp < 16; ++pp) {
        const int cb0 = pbase + (pp << 4);
        float acc0 = 0.0f, acc1 = 0.0f;
        #pragma unroll
        for (int cb = 0; cb < 16; cb += 4) {
            const float b0 = Wb[cb0+cb+0], b1 = Wb[cb0+cb+1];
            const float b2 = Wb[cb0+cb+2], b3 = Wb[cb0+cb+3];
            float u00=b0,u01=b1,u02=b2,u03=b3;
            float u10=b0,u11=b1,u12=b2,u13=b3;
            #pragma unroll
            for (int cp = 0; cp < 16; ++cp) {
                const float4 f = *(const float4*)&wlds[(cp << 9) + cb0 + cb];
                u00 = fmaf(xr0[cp], f.x, u00);
                u01 = fmaf(xr0[cp], f.y, u01);
                u02 = fmaf(xr0[cp], f.z, u02);
                u03 = fmaf(xr0[cp], f.w, u03);
                u10 = fmaf(xr1[cp], f.x, u10);
                u11 = fmaf(xr1[cp], f.y, u11);
                u12 = fmaf(xr1[cp], f.z, u12);
                u13 = fmaf(xr1[cp], f.w, u13);
            }
            acc0 = fmaf(xr0[cb+0], u00, acc0);
            acc0 = fmaf(xr0[cb+1], u01, acc0);
            acc0 = fmaf(xr0[cb+2], u02, acc0);
            acc0 = fmaf(xr0[cb+3], u03, acc0);
            acc1 = fmaf(xr1[cb+0], u10, acc1);
            acc1 = fmaf(xr1[cb+1], u11, acc1);
            acc1 = fmaf(xr1[cb+2], u12, acc1);
            acc1 = fmaf(xr1[cb+3], u13, acc1);
        }
        const float bv = Bv[(h << 4) + pp];
        const float z0 = aF[tid * 34 + pp]      * wgt0 + acc0 + bv;
        const float z1 = aF[tid * 34 + 17 + pp] * wgt1 + acc1 + bv;
        const float cv0 = 1.0f / (1.0f + expf(-z0));
        const float cv1 = 1.0f / (1.0f + expf(-z1));
        conv[(size_t)i0 * 32 + (h << 4) + pp] = cv0;
        conv[(size_t)i1 * 32 + (h << 4) + pp] = cv1;
        float v = cv0 + cv1;
        v += __shfl_xor(v, 1);
        v += __shfl_xor(v, 2);
        v += __shfl_xor(v, 4);
        v += __shfl_xor(v, 8);
        v += __shfl_xor(v, 16);
        v += __shfl_xor(v, 32);
        if (lane == 0) atomicAdd(&S2s[n * 32 + (h << 4) + pp], v);
    }
    // S1: x sums — h==0 wave covers each node exactly once (i0 and i1)
    if (h == 0) {
        #pragma unroll
        for (int c = 0; c < 16; ++c) {
            float v = xr0[c] + xr1[c];
            v += __shfl_xor(v, 1);
            v += __shfl_xor(v, 2);
            v += __shfl_xor(v, 4);
            v += __shfl_xor(v, 8);
            v += __shfl_xor(v, 16);
            v += __shfl_xor(v, 32);
            if (lane == 0) atomicAdd(&S1s[n * 32 + c], v);
        }
    }
}

// ---------------------------------------------------------------- gate
__global__ void gate_kernel(const float* __restrict__ S1s, const float* __restrict__ S2s,
    const float* __restrict__ m1W, const float* __restrict__ m1b,
    const float* __restrict__ m2W, const float* __restrict__ m2b,
    float* __restrict__ M0, float* __restrict__ M1, float invI)
{
    int t = threadIdx.x;              // N*32 threads
    int n = t >> 5, p = t & 31;
    float z1 = m1b[p], z2 = m2b[p];
    #pragma unroll
    for (int q = 0; q < 32; ++q) {
        z1 = fmaf(S1s[n * 32 + q] * invI, m1W[q * 32 + p], z1);
        z2 = fmaf(S2s[n * 32 + q] * invI, m2W[q * 32 + p], z2);
    }
    float m = fmaxf(z1, z2);
    float e1 = expf(z1 - m), e2 = expf(z2 - m);
    float inv = 1.0f / (e1 + e2);
    M0[t] = e1 * inv;
    M1[t] = e2 * inv;
}

// ---------------------------------------------------------------- fuse+pool
// Grid-stride over nodes; per-block LDS max-table; block table -> blkT.
__global__ __launch_bounds__(256) void pool_kernel(
    const float* __restrict__ x, const float* __restrict__ conv,
    const int* __restrict__ cl, const float* __restrict__ M0,
    const float* __restrict__ M1, unsigned* __restrict__ blkT,
    int NI, int nSlots)
{
    __shared__ unsigned utab[4096];   // nC*32 <= 4096 (nC = 128 here)
    const int tid = threadIdx.x;
    for (int t = tid; t < nSlots; t += 256) utab[t] = 0u;
    __syncthreads();

    for (int i = blockIdx.x * 256 + tid; i < NI; i += POOL_NBLK * 256) {
        int n = i >> 12;
        int c = cl[i];
        const float* m0 = M0 + n * 32;
        const float* m1 = M1 + n * 32;
        float cr[32];
        {
            const float4* q = (const float4*)(conv + (size_t)i * 32);
            #pragma unroll
            for (int b = 0; b < 8; ++b) {
                float4 v = q[b];
                cr[b*4+0] = v.x; cr[b*4+1] = v.y; cr[b*4+2] = v.z; cr[b*4+3] = v.w;
            }
        }
        float xr[16];
        load16(x + (size_t)i * 16, xr);
        unsigned* up = utab + (c << 5);
        #pragma unroll
        for (int p = 0; p < 16; ++p) {
            float f = fmaf(m0[p], xr[p], m1[p] * cr[p]);
            atomicMax(&up[p], fmap(f));
        }
        #pragma unroll
        for (int p = 16; p < 32; ++p) {
            float f = m1[p] * cr[p];   // x_pad is zero for p >= 16
            atomicMax(&up[p], fmap(f));
        }
    }
    __syncthreads();
    unsigned* dst = blkT + (size_t)blockIdx.x * nSlots;
    for (int t = tid; t < nSlots; t += 256) dst[t] = utab[t];
}

__global__ __launch_bounds__(256) void pool_reduce(
    const unsigned* __restrict__ blkT, unsigned* __restrict__ pooledM, int nSlots)
{
    int t = blockIdx.x * 256 + threadIdx.x;
    if (t >= nSlots) return;
    unsigned m = 0u;
    #pragma unroll 8
    for (int b = 0; b < POOL_NBLK; ++b)
        m = max(m, blkT[(size_t)b * nSlots + t]);
    pooledM[t] = m;
}

// ---------------------------------------------------------------- final
__global__ void final_kernel(const unsigned* __restrict__ pooledM,
    const float* __restrict__ scW, const float* __restrict__ scb,
    const float* __restrict__ lr, float* __restrict__ out, int total)
{
    int t = blockIdx.x * 256 + threadIdx.x;
    if (t >= total) return;
    int g = t >> 5, p = t & 31;
    float acc = scb[p];
    float self = 0.0f;
    #pragma unroll
    for (int q = 0; q < 32; ++q) {
        float v = funmap(pooledM[g * 32 + q]);
        if (q == p) self = v;
        acc = fmaf(v, scW[q * 32 + p], acc);
    }
    out[t] = self + lr[0] * acc;
}

extern "C" void kernel_launch(void* const* d_in, const int* in_sizes, int n_in,
                              void* d_out, int out_size, void* d_ws, size_t ws_size,
                              hipStream_t stream)
{
    const float* x   = (const float*)d_in[0];
    const int*   ei  = (const int*)d_in[1];
    const int*   clus= (const int*)d_in[2];
    const float* Fw  = (const float*)d_in[3];
    const float* Fb  = (const float*)d_in[4];
    const float* Ww  = (const float*)d_in[5];
    const float* Wb  = (const float*)d_in[6];
    const float* Mw  = (const float*)d_in[7];
    const float* Mb  = (const float*)d_in[8];
    const float* Bv  = (const float*)d_in[9];
    const float* m1W = (const float*)d_in[10];
    const float* m1b = (const float*)d_in[11];
    const float* m2W = (const float*)d_in[12];
    const float* m2b = (const float*)d_in[13];
    const float* scW = (const float*)d_in[14];
    const float* scb = (const float*)d_in[15];
    const float* lr  = (const float*)d_in[16];

    const int NI = in_sizes[0] / 16;   // 65536 nodes
    const int E  = in_sizes[1] / 2;    // 589824 edges
    const int nG = NI >> 12;           // clouds (I = 4096)
    const int nC = out_size / 32;      // clusters = K*N
    const int nSlots = nC * 32;        // 4096

    // ws layout (f32 elems): s[NI*16] | deg[NI] | S1s[nG*32] | S2s[nG*32] |
    //                        pooledM[nSlots u32] | M0[nG*32] | M1[nG*32] | conv[NI*32]
    // s_ (4 MB) dead after node_update -> reused as blkT (256 x 16 KB = 4 MB).
    float* ws   = (float*)d_ws;
    float* s_   = ws;
    float* deg_ = s_ + (size_t)NI * 16;
    float* S1s  = deg_ + NI;
    float* S2s  = S1s + nG * 32;
    unsigned* pooledM = (unsigned*)(S2s + nG * 32);
    float* M0   = (float*)(pooledM + nSlots);
    float* M1   = M0 + nG * 32;
    float* conv = M1 + nG * 32;
    unsigned* blkT = (unsigned*)s_;    // POOL_NBLK * nSlots * 4 B = 4 MB <= s_

    size_t need_bytes = (size_t)((char*)(conv + (size_t)NI * 32) - (char*)ws);
    if (ws_size < need_bytes || nSlots > 4096) return;
    if ((size_t)POOL_NBLK * nSlots > (size_t)NI * 16) return;  // blkT must fit s_

    size_t zbytes = (size_t)((char*)(pooledM + nSlots) - (char*)ws);
    hipMemsetAsync(d_ws, 0, zbytes, stream);   // zeros s, deg, S1s, S2s, pooledM

    edge_scatter<<<dim3((E * 16 + 255) / 256), dim3(256), 0, stream>>>(x, ei, s_, deg_, E);
    node_update<<<dim3(NI / 128), dim3(128), 0, stream>>>(
        x, s_, deg_, Fw, Fb, Ww, Wb, Mw, Mb, Bv, conv, S1s, S2s);
    gate_kernel<<<dim3(1), dim3(nG * 32), 0, stream>>>(
        S1s, S2s, m1W, m1b, m2W, m2b, M0, M1, 1.0f / 4096.0f);
    pool_kernel<<<dim3(POOL_NBLK), dim3(256), 0, stream>>>(
        x, conv, clus, M0, M1, blkT, NI, nSlots);
    pool_reduce<<<dim3((nSlots + 255) / 256), dim3(256), 0, stream>>>(
        blkT, pooledM, nSlots);
    final_kernel<<<dim3((out_size + 255) / 256), dim3(256), 0, stream>>>(
        pooledM, scW, scb, lr, (float*)d_out, out_size);
}

// Round 16
// 223.627 us; speedup vs baseline: 2.0512x; 1.2013x over previous
//
#include <hip/hip_runtime.h>
#include <hip/hip_bf16.h>

// ShrinkingUnit: N=16, I=4096, C=16, P=16, K=8, CP=32, NI=65536.
// aggr[i,p] = sum_c x_i[c]*(sum_c' tbar[c'] F_W[c',p*16+c] + F_b[p*16+c]),
//   tbar_i = s_i/deg_i - x_i.
// R11: per-lane h -> 16.8M bank-conflict cyc. R12: wave-uniform h -> 0
//   conflicts, 91us (LDS-issue bound: 16384 b128/CU x 12cyc = 82us).
// R15: NB=2 @128thr halved LDS instrs BUT waves/CU 8->4 (1/SIMD) -> latency
//   exposed, 98.7us, occ 9.8%. Fix: pp-split 2-way x NB=2 @256thr -> wave
//   count restored (8/CU, 2/SIMD) AND per-CU LDS instrs stay halved
//   (8192 b128/CU = 41us issue floor).
// Pool: hierarchical LDS tables, POOL_NBLK=256 (R8: global atomicMax = 186us).

#define POOL_NBLK 256

__device__ __forceinline__ unsigned fmap(float f) {
    unsigned u = __float_as_uint(f);
    return (u & 0x80000000u) ? ~u : (u | 0x80000000u);   // order-preserving map
}
__device__ __forceinline__ float funmap(unsigned m) {
    return (m & 0x80000000u) ? __uint_as_float(m & 0x7FFFFFFFu)
                             : __uint_as_float(~m);
}

__device__ __forceinline__ void load16(const float* __restrict__ p, float* r) {
    const float4* q = (const float4*)p;
    float4 a = q[0], b = q[1], c = q[2], d = q[3];
    r[0]=a.x; r[1]=a.y; r[2]=a.z; r[3]=a.w;
    r[4]=b.x; r[5]=b.y; r[6]=b.z; r[7]=b.w;
    r[8]=c.x; r[9]=c.y; r[10]=c.z; r[11]=c.w;
    r[12]=d.x; r[13]=d.y; r[14]=d.z; r[15]=d.w;
}

// ---------------------------------------------------------------- edges
__global__ __launch_bounds__(256) void edge_scatter(
    const float* __restrict__ x, const int* __restrict__ ei,
    float* __restrict__ s, float* __restrict__ deg, int E)
{
    int tid = blockIdx.x * 256 + threadIdx.x;
    int e = tid >> 4, c = tid & 15;
    if (e >= E) return;
    int src = ei[e];          // row 0 = src
    int dst = ei[E + e];      // row 1 = dst
    atomicAdd(&s[(size_t)dst * 16 + c], x[(size_t)src * 16 + c]);
    if (c == 0) atomicAdd(&deg[dst], 1.0f);
}

// ---------------------------------------------------------------- nodes
// 256 threads = 4 waves; wave = (h = tid>>7, ph = (tid>>6)&1) handles 8 p's
// (p = h*16+ph*8+pp) for nodes i0 = blk*128+lane, i1 = i0+64 (NB=2).
// All weight reads wave-uniform -> LDS broadcast, 0 conflicts.
// aF LDS row = tid*17: [0..7]=node0 pp, [8..15]=node1 pp, [16]=pad (odd
// stride -> conflict-free).
__global__ __launch_bounds__(256) void node_update(
    const float* __restrict__ x, const float* __restrict__ s,
    const float* __restrict__ deg,
    const float* __restrict__ Fw, const float* __restrict__ Fb,
    const float* __restrict__ Ww, const float* __restrict__ Wb,
    const float* __restrict__ Mw, const float* __restrict__ Mb,
    const float* __restrict__ Bv,
    float* __restrict__ conv, float* __restrict__ S1s, float* __restrict__ S2s)
{
    __shared__ float wlds[8192];      // 16 x 512 weight tile (F, then W)
    __shared__ float aF[256 * 17];    // per-thread 2 nodes x 8 pp, pad to 17
    const int tid = threadIdx.x;

    {   // stage F: 2048 float4 / 256 threads = 8 each
        const float4* F4 = (const float4*)Fw;
        float4* w4 = (float4*)wlds;
        #pragma unroll
        for (int k = 0; k < 8; ++k) w4[k * 256 + tid] = F4[k * 256 + tid];
    }

    const int lane = tid & 63;
    const int ph   = (tid >> 6) & 1;           // p-half within h (wave-uniform)
    const int h    = tid >> 7;                 // CP half (wave-uniform)
    const int i0   = blockIdx.x * 128 + lane;  // node A
    const int i1   = i0 + 64;                  // node B
    const int n    = i0 >> 12;                 // cloud (128 | 4096)

    float xr0[16], tr0[16], xr1[16], tr1[16];
    load16(x + (size_t)i0 * 16, xr0);
    load16(s + (size_t)i0 * 16, tr0);
    load16(x + (size_t)i1 * 16, xr1);
    load16(s + (size_t)i1 * 16, tr1);
    const float invd0 = 1.0f / deg[i0];
    const float invd1 = 1.0f / deg[i1];
    #pragma unroll
    for (int c = 0; c < 16; ++c) {
        tr0[c] = tr0[c] * invd0 - xr0[c];
        tr1[c] = tr1[c] * invd1 - xr1[c];
    }

    __syncthreads();                  // F staged

    const int colbase = (h << 8) + (ph << 7);  // (h*16+ph*8)*16
    // phase 1: aF[nb][pp] = x^T (tbar^T F)_p
    #pragma unroll 1
    for (int pp = 0; pp < 8; ++pp) {
        const int cb0 = colbase + (pp << 4);
        float acc0 = 0.0f, acc1 = 0.0f;
        #pragma unroll
        for (int cb = 0; cb < 16; cb += 4) {
            const float b0 = Fb[cb0+cb+0], b1 = Fb[cb0+cb+1];
            const float b2 = Fb[cb0+cb+2], b3 = Fb[cb0+cb+3];
            float u00=b0,u01=b1,u02=b2,u03=b3;
            float u10=b0,u11=b1,u12=b2,u13=b3;
            #pragma unroll
            for (int cp = 0; cp < 16; ++cp) {
                const float4 f = *(const float4*)&wlds[(cp << 9) + cb0 + cb];
                u00 = fmaf(tr0[cp], f.x, u00);
                u01 = fmaf(tr0[cp], f.y, u01);
                u02 = fmaf(tr0[cp], f.z, u02);
                u03 = fmaf(tr0[cp], f.w, u03);
                u10 = fmaf(tr1[cp], f.x, u10);
                u11 = fmaf(tr1[cp], f.y, u11);
                u12 = fmaf(tr1[cp], f.z, u12);
                u13 = fmaf(tr1[cp], f.w, u13);
            }
            acc0 = fmaf(xr0[cb+0], u00, acc0);
            acc0 = fmaf(xr0[cb+1], u01, acc0);
            acc0 = fmaf(xr0[cb+2], u02, acc0);
            acc0 = fmaf(xr0[cb+3], u03, acc0);
            acc1 = fmaf(xr1[cb+0], u10, acc1);
            acc1 = fmaf(xr1[cb+1], u11, acc1);
            acc1 = fmaf(xr1[cb+2], u12, acc1);
            acc1 = fmaf(xr1[cb+3], u13, acc1);
        }
        aF[tid * 17 + pp]     = acc0;
        aF[tid * 17 + 8 + pp] = acc1;
    }
    __syncthreads();                  // F reads + aF writes done
    {   // re-stage W
        const float4* W4 = (const float4*)Ww;
        float4* w4 = (float4*)wlds;
        #pragma unroll
        for (int k = 0; k < 8; ++k) w4[k * 256 + tid] = W4[k * 256 + tid];
    }

    // weight = aggr @ M_W + M_b: gather all 4 waves' aF slices for own nodes
    float wgt0 = Mb[0], wgt1 = Mb[0];
    #pragma unroll
    for (int wv = 0; wv < 4; ++wv) {           // wv = h*2 + ph
        const int base = (wv * 64 + lane) * 17;
        const int qoff = wv * 8;               // p = (wv>>1)*16 + (wv&1)*8 + q
        #pragma unroll
        for (int q = 0; q < 8; ++q) {
            wgt0 = fmaf(aF[base + q],     Mw[qoff + q], wgt0);
            wgt1 = fmaf(aF[base + 8 + q], Mw[qoff + q], wgt1);
        }
    }
    __syncthreads();                  // W staged; aF reads done

    // phase 2: + x^T (x^T W)_p, sigmoid, conv, S2 reduce
    #pragma unroll 1
    for (int pp = 0; pp < 8; ++pp) {
        const int cb0 = colbase + (pp << 4);
        float acc0 = 0.0f, acc1 = 0.0f;
        #pragma unroll
        for (int cb = 0; cb < 16; cb += 4) {
            const float b0 = Wb[cb0+cb+0], b1 = Wb[cb0+cb+1];
            const float b2 = Wb[cb0+cb+2], b3 = Wb[cb0+cb+3];
            float u00=b0,u01=b1,u02=b2,u03=b3;
            float u10=b0,u11=b1,u12=b2,u13=b3;
            #pragma unroll
            for (int cp = 0; cp < 16; ++cp) {
                const float4 f = *(const float4*)&wlds[(cp << 9) + cb0 + cb];
                u00 = fmaf(xr0[cp], f.x, u00);
                u01 = fmaf(xr0[cp], f.y, u01);
                u02 = fmaf(xr0[cp], f.z, u02);
                u03 = fmaf(xr0[cp], f.w, u03);
                u10 = fmaf(xr1[cp], f.x, u10);
                u11 = fmaf(xr1[cp], f.y, u11);
                u12 = fmaf(xr1[cp], f.z, u12);
                u13 = fmaf(xr1[cp], f.w, u13);
            }
            acc0 = fmaf(xr0[cb+0], u00, acc0);
            acc0 = fmaf(xr0[cb+1], u01, acc0);
            acc0 = fmaf(xr0[cb+2], u02, acc0);
            acc0 = fmaf(xr0[cb+3], u03, acc0);
            acc1 = fmaf(xr1[cb+0], u10, acc1);
            acc1 = fmaf(xr1[cb+1], u11, acc1);
            acc1 = fmaf(xr1[cb+2], u12, acc1);
            acc1 = fmaf(xr1[cb+3], u13, acc1);
        }
        const int pcol = (h << 4) + (ph << 3) + pp;
        const float bv = Bv[pcol];
        const float z0 = aF[tid * 17 + pp]     * wgt0 + acc0 + bv;
        const float z1 = aF[tid * 17 + 8 + pp] * wgt1 + acc1 + bv;
        const float cv0 = 1.0f / (1.0f + expf(-z0));
        const float cv1 = 1.0f / (1.0f + expf(-z1));
        conv[(size_t)i0 * 32 + pcol] = cv0;
        conv[(size_t)i1 * 32 + pcol] = cv1;
        float v = cv0 + cv1;
        v += __shfl_xor(v, 1);
        v += __shfl_xor(v, 2);
        v += __shfl_xor(v, 4);
        v += __shfl_xor(v, 8);
        v += __shfl_xor(v, 16);
        v += __shfl_xor(v, 32);
        if (lane == 0) atomicAdd(&S2s[n * 32 + pcol], v);
    }
    // S1: x sums — wave (h=0, ph=0) covers nodes i0 and i1 exactly once
    if (tid < 64) {
        #pragma unroll
        for (int c = 0; c < 16; ++c) {
            float v = xr0[c] + xr1[c];
            v += __shfl_xor(v, 1);
            v += __shfl_xor(v, 2);
            v += __shfl_xor(v, 4);
            v += __shfl_xor(v, 8);
            v += __shfl_xor(v, 16);
            v += __shfl_xor(v, 32);
            if (lane == 0) atomicAdd(&S1s[n * 32 + c], v);
        }
    }
}

// ---------------------------------------------------------------- gate
__global__ void gate_kernel(const float* __restrict__ S1s, const float* __restrict__ S2s,
    const float* __restrict__ m1W, const float* __restrict__ m1b,
    const float* __restrict__ m2W, const float* __restrict__ m2b,
    float* __restrict__ M0, float* __restrict__ M1, float invI)
{
    int t = threadIdx.x;              // N*32 threads
    int n = t >> 5, p = t & 31;
    float z1 = m1b[p], z2 = m2b[p];
    #pragma unroll
    for (int q = 0; q < 32; ++q) {
        z1 = fmaf(S1s[n * 32 + q] * invI, m1W[q * 32 + p], z1);
        z2 = fmaf(S2s[n * 32 + q] * invI, m2W[q * 32 + p], z2);
    }
    float m = fmaxf(z1, z2);
    float e1 = expf(z1 - m), e2 = expf(z2 - m);
    float inv = 1.0f / (e1 + e2);
    M0[t] = e1 * inv;
    M1[t] = e2 * inv;
}

// ---------------------------------------------------------------- fuse+pool
__global__ __launch_bounds__(256) void pool_kernel(
    const float* __restrict__ x, const float* __restrict__ conv,
    const int* __restrict__ cl, const float* __restrict__ M0,
    const float* __restrict__ M1, unsigned* __restrict__ blkT,
    int NI, int nSlots)
{
    __shared__ unsigned utab[4096];   // nC*32 <= 4096 (nC = 128 here)
    const int tid = threadIdx.x;
    for (int t = tid; t < nSlots; t += 256) utab[t] = 0u;
    __syncthreads();

    for (int i = blockIdx.x * 256 + tid; i < NI; i += POOL_NBLK * 256) {
        int n = i >> 12;
        int c = cl[i];
        const float* m0 = M0 + n * 32;
        const float* m1 = M1 + n * 32;
        float cr[32];
        {
            const float4* q = (const float4*)(conv + (size_t)i * 32);
            #pragma unroll
            for (int b = 0; b < 8; ++b) {
                float4 v = q[b];
                cr[b*4+0] = v.x; cr[b*4+1] = v.y; cr[b*4+2] = v.z; cr[b*4+3] = v.w;
            }
        }
        float xr[16];
        load16(x + (size_t)i * 16, xr);
        unsigned* up = utab + (c << 5);
        #pragma unroll
        for (int p = 0; p < 16; ++p) {
            float f = fmaf(m0[p], xr[p], m1[p] * cr[p]);
            atomicMax(&up[p], fmap(f));
        }
        #pragma unroll
        for (int p = 16; p < 32; ++p) {
            float f = m1[p] * cr[p];   // x_pad is zero for p >= 16
            atomicMax(&up[p], fmap(f));
        }
    }
    __syncthreads();
    unsigned* dst = blkT + (size_t)blockIdx.x * nSlots;
    for (int t = tid; t < nSlots; t += 256) dst[t] = utab[t];
}

__global__ __launch_bounds__(256) void pool_reduce(
    const unsigned* __restrict__ blkT, unsigned* __restrict__ pooledM, int nSlots)
{
    int t = blockIdx.x * 256 + threadIdx.x;
    if (t >= nSlots) return;
    unsigned m = 0u;
    #pragma unroll 8
    for (int b = 0; b < POOL_NBLK; ++b)
        m = max(m, blkT[(size_t)b * nSlots + t]);
    pooledM[t] = m;
}

// ---------------------------------------------------------------- final
__global__ void final_kernel(const unsigned* __restrict__ pooledM,
    const float* __restrict__ scW, const float* __restrict__ scb,
    const float* __restrict__ lr, float* __restrict__ out, int total)
{
    int t = blockIdx.x * 256 + threadIdx.x;
    if (t >= total) return;
    int g = t >> 5, p = t & 31;
    float acc = scb[p];
    float self = 0.0f;
    #pragma unroll
    for (int q = 0; q < 32; ++q) {
        float v = funmap(pooledM[g * 32 + q]);
        if (q == p) self = v;
        acc = fmaf(v, scW[q * 32 + p], acc);
    }
    out[t] = self + lr[0] * acc;
}

extern "C" void kernel_launch(void* const* d_in, const int* in_sizes, int n_in,
                              void* d_out, int out_size, void* d_ws, size_t ws_size,
                              hipStream_t stream)
{
    const float* x   = (const float*)d_in[0];
    const int*   ei  = (const int*)d_in[1];
    const int*   clus= (const int*)d_in[2];
    const float* Fw  = (const float*)d_in[3];
    const float* Fb  = (const float*)d_in[4];
    const float* Ww  = (const float*)d_in[5];
    const float* Wb  = (const float*)d_in[6];
    const float* Mw  = (const float*)d_in[7];
    const float* Mb  = (const float*)d_in[8];
    const float* Bv  = (const float*)d_in[9];
    const float* m1W = (const float*)d_in[10];
    const float* m1b = (const float*)d_in[11];
    const float* m2W = (const float*)d_in[12];
    const float* m2b = (const float*)d_in[13];
    const float* scW = (const float*)d_in[14];
    const float* scb = (const float*)d_in[15];
    const float* lr  = (const float*)d_in[16];

    const int NI = in_sizes[0] / 16;   // 65536 nodes
    const int E  = in_sizes[1] / 2;    // 589824 edges
    const int nG = NI >> 12;           // clouds (I = 4096)
    const int nC = out_size / 32;      // clusters = K*N
    const int nSlots = nC * 32;        // 4096

    // ws layout (f32 elems): s[NI*16] | deg[NI] | S1s[nG*32] | S2s[nG*32] |
    //                        pooledM[nSlots u32] | M0[nG*32] | M1[nG*32] | conv[NI*32]
    // s_ (4 MB) dead after node_update -> reused as blkT (256 x 16 KB = 4 MB).
    float* ws   = (float*)d_ws;
    float* s_   = ws;
    float* deg_ = s_ + (size_t)NI * 16;
    float* S1s  = deg_ + NI;
    float* S2s  = S1s + nG * 32;
    unsigned* pooledM = (unsigned*)(S2s + nG * 32);
    float* M0   = (float*)(pooledM + nSlots);
    float* M1   = M0 + nG * 32;
    float* conv = M1 + nG * 32;
    unsigned* blkT = (unsigned*)s_;    // POOL_NBLK * nSlots * 4 B = 4 MB <= s_

    size_t need_bytes = (size_t)((char*)(conv + (size_t)NI * 32) - (char*)ws);
    if (ws_size < need_bytes || nSlots > 4096) return;
    if ((size_t)POOL_NBLK * nSlots > (size_t)NI * 16) return;  // blkT must fit s_

    size_t zbytes = (size_t)((char*)(pooledM + nSlots) - (char*)ws);
    hipMemsetAsync(d_ws, 0, zbytes, stream);   // zeros s, deg, S1s, S2s, pooledM

    edge_scatter<<<dim3((E * 16 + 255) / 256), dim3(256), 0, stream>>>(x, ei, s_, deg_, E);
    node_update<<<dim3(NI / 128), dim3(256), 0, stream>>>(
        x, s_, deg_, Fw, Fb, Ww, Wb, Mw, Mb, Bv, conv, S1s, S2s);
    gate_kernel<<<dim3(1), dim3(nG * 32), 0, stream>>>(
        S1s, S2s, m1W, m1b, m2W, m2b, M0, M1, 1.0f / 4096.0f);
    pool_kernel<<<dim3(POOL_NBLK), dim3(256), 0, stream>>>(
        x, conv, clus, M0, M1, blkT, NI, nSlots);
    pool_reduce<<<dim3((nSlots + 255) / 256), dim3(256), 0, stream>>>(
        blkT, pooledM, nSlots);
    final_kernel<<<dim3((out_size + 255) / 256), dim3(256), 0, stream>>>(
        pooledM, scW, scb, lr, (float*)d_out, out_size);
}